// Round 10
// baseline (443.119 us; speedup 1.0000x reference)
//
#include <hip/hip_runtime.h>
#include <hip/hip_fp16.h>

// K-Planes feature field: N=1M points, C=32 channels, 3 pairs, 3 resolutions.
// out[n, r*32 + c] = prod_p bilinear(plane[r][p][c], coords_p(n))
//
// R9 strategy:
//  - pre-pass: EXACT R3 kernels (3 specialized transposes, zero, hist, scan,
//    scatter) — R9's fused prep regressed, reverted.
//  - sampler: row-pair loads (2x16B per res,pair instead of 4x8B; halves VMEM
//    instructions) with x-corner exchange via DPP quad_perm (lane^1) — pure
//    VALU, no DS pipe (R8's shfl_xor cost 1.13e8 LDS-conflict cycles).

constexpr int kN = 1048576;
constexpr int kC = 32;
constexpr int kCells = 32 * 32 * 32;   // 15-bit Morton key

typedef float f32x4 __attribute__((ext_vector_type(4)));
typedef short s16x8 __attribute__((ext_vector_type(8)));

// ---- transpose+convert (3, C, R, R) fp32 -> (3, R, R, C) fp16 (R3 exact) ----
__global__ __launch_bounds__(1024) void kp_transpose_h(const float* __restrict__ in,
                                                       __half* __restrict__ out, int R) {
    __shared__ float tile[32][33];
    const int tx = threadIdx.x, ty = threadIdx.y;
    const int x0 = blockIdx.x * 32;
    const int y  = blockIdx.y;
    const int p  = blockIdx.z;
    tile[ty][tx] = in[(((size_t)p * kC + ty) * R + y) * R + x0 + tx];
    __syncthreads();
    out[(((size_t)p * R + y) * R + x0 + ty) * kC + tx] = __float2half_rn(tile[tx][ty]);
}

// ---- Morton cell key from coords in [-1,1] ----
__device__ __forceinline__ unsigned cell_key(float x, float y, float z) {
    int cx = min(max((int)((x + 1.f) * 16.f), 0), 31);
    int cy = min(max((int)((y + 1.f) * 16.f), 0), 31);
    int cz = min(max((int)((z + 1.f) * 16.f), 0), 31);
    unsigned m = 0;
#pragma unroll
    for (int b = 0; b < 5; ++b) {
        m |= ((unsigned)((cx >> b) & 1)) << (3 * b);
        m |= ((unsigned)((cy >> b) & 1)) << (3 * b + 1);
        m |= ((unsigned)((cz >> b) & 1)) << (3 * b + 2);
    }
    return m;
}

__global__ __launch_bounds__(256) void kp_zero(unsigned* __restrict__ p, int n) {
    int i = blockIdx.x * 256 + threadIdx.x;
    if (i < n) p[i] = 0u;
}

__global__ __launch_bounds__(256) void kp_hist(const float* __restrict__ xs,
                                               unsigned* __restrict__ hist) {
    int n = blockIdx.x * 256 + threadIdx.x;
    float x = xs[n * 3 + 0], y = xs[n * 3 + 1], z = xs[n * 3 + 2];
    atomicAdd(&hist[cell_key(x, y, z)], 1u);
}

// single-block exclusive scan of kCells entries -> cursor
__global__ __launch_bounds__(1024) void kp_scan(const unsigned* __restrict__ hist,
                                                unsigned* __restrict__ cursor) {
    __shared__ unsigned sums[1024];
    const int t = threadIdx.x;
    const int per = kCells / 1024;          // 32
    unsigned local[32];
    unsigned s = 0;
    const int base = t * per;
#pragma unroll
    for (int i = 0; i < per; ++i) { local[i] = hist[base + i]; s += local[i]; }
    sums[t] = s;
    __syncthreads();
    for (int off = 1; off < 1024; off <<= 1) {
        unsigned v = (t >= off) ? sums[t - off] : 0u;
        __syncthreads();
        sums[t] += v;
        __syncthreads();
    }
    unsigned run = (t == 0) ? 0u : sums[t - 1];   // exclusive prefix
#pragma unroll
    for (int i = 0; i < per; ++i) { cursor[base + i] = run; run += local[i]; }
}

__global__ __launch_bounds__(256) void kp_scatter(const float* __restrict__ xs,
                                                  unsigned* __restrict__ cursor,
                                                  f32x4* __restrict__ sorted) {
    int n = blockIdx.x * 256 + threadIdx.x;
    float x = xs[n * 3 + 0], y = xs[n * 3 + 1], z = xs[n * 3 + 2];
    unsigned pos = atomicAdd(&cursor[cell_key(x, y, z)], 1u);
    f32x4 v = {x, y, z, __uint_as_float((unsigned)n)};
    __builtin_nontemporal_store(v, &sorted[pos]);
}

// ---- DPP lane^1 exchange: quad_perm [1,0,3,2] = 0xB1; pure VALU, no LDS ----
__device__ __forceinline__ int dpp_xor1(int v) {
    return __builtin_amdgcn_update_dpp(v, v, 0xB1, 0xF, 0xF, false);
}

// ---- fused sampler: 8 lanes/point; per (res,pair) two 16B row-pair loads ----
// lane l: side = l&1 (x-corner), q = l>>1 (channel slice of 8).
// loads halfs [side*32 + q*8 .. +8) of the 128B block {x0 ch0-31 | x1 ch0-31}
// at rows y0 and y1; y-interp + x-weight local; lane^1 DPP exchange of 4 fp16
// partials completes the bilinear sum. planes = contiguous {t128|t256|t512}.
__global__ __launch_bounds__(256) void kp_sample_dpp(const f32x4* __restrict__ pts,
                                                     const __half* __restrict__ planes,
                                                     float* __restrict__ out) {
    constexpr unsigned offr[3] = {0u,
                                  3u * 128 * 128 * 32,
                                  3u * 128 * 128 * 32 + 3u * 256 * 256 * 32};
    const int nwg = (kN * 8) / 256;                 // 32768, %8 == 0
    int bid = blockIdx.x;
    bid = (bid & 7) * (nwg / 8) + (bid >> 3);       // XCD-contiguous chunks
    const int li = threadIdx.x;
    const int n    = bid * 32 + (li >> 3);          // sorted point index
    const int l    = li & 7;
    const int side = l & 1;                         // 0: x0, 1: x0+1
    const int q    = l >> 1;                        // channel slice (8 ch)
    f32x4 pt = pts[n];
    const float a = pt.x, b = pt.y, d = pt.z;
    const unsigned oi = __float_as_uint(pt.w);
    // PAIRS = (0,1),(0,2),(1,2); coords last dim = (gx, gy)
    const float gx[3] = {a, a, b};
    const float gy[3] = {b, d, d};
    // lane stores channels q*8 + side*4 .. +4
    float* o = out + (size_t)oi * 96 + q * 8 + side * 4;

#pragma unroll
    for (int r = 0; r < 3; ++r) {
        const int R = 128 << r;
        const float fr = (float)(R - 1);
        float prod[4] = {1.f, 1.f, 1.f, 1.f};
#pragma unroll
        for (int p = 0; p < 3; ++p) {
            float ix = (gx[p] + 1.f) * 0.5f * fr;
            float iy = (gy[p] + 1.f) * 0.5f * fr;
            // clamp base to R-2: preserves exact align_corners semantics
            // (at ix==R-1: wx=1 -> full weight on x1=R-1), no min() on x1/y1
            float x0f = fminf(fmaxf(floorf(ix), 0.f), (float)(R - 2));
            float y0f = fminf(fmaxf(floorf(iy), 0.f), (float)(R - 2));
            float wx = ix - x0f, wy = iy - y0f;
            unsigned xi0 = (unsigned)x0f, yi0 = (unsigned)y0f;
            const __half* pb = planes + offr[r] + (size_t)p * R * R * 32
                             + (size_t)xi0 * 32u + (unsigned)(side * 32 + q * 8);
            union U { s16x8 v; __half2 h[4]; } A, B;
            A.v = *reinterpret_cast<const s16x8*>(pb + (size_t)yi0 * R * 32u);
            B.v = *reinterpret_cast<const s16x8*>(pb + (size_t)(yi0 + 1) * R * 32u);
            const float xw = side ? wx : (1.f - wx);
            float part[8];
#pragma unroll
            for (int j = 0; j < 4; ++j) {
                float2 fa = __half22float2(A.h[j]);
                float2 fb = __half22float2(B.h[j]);
                part[2 * j]     = (fa.x + wy * (fb.x - fa.x)) * xw;
                part[2 * j + 1] = (fa.y + wy * (fb.y - fa.y)) * xw;
            }
            // send partner's stored window ((1-side)*4..+4) as 4 fp16;
            // receive partner's partials for mine (side*4..+4)
            const int pw = 4 - side * 4;
            __half2 s0 = __floats2half2_rn(part[pw],     part[pw + 1]);
            __half2 s1 = __floats2half2_rn(part[pw + 2], part[pw + 3]);
            int e0 = dpp_xor1(__builtin_bit_cast(int, s0));
            int e1 = dpp_xor1(__builtin_bit_cast(int, s1));
            float2 g0 = __half22float2(__builtin_bit_cast(__half2, e0));
            float2 g1 = __half22float2(__builtin_bit_cast(__half2, e1));
            const int mw = side * 4;
            prod[0] *= part[mw]     + g0.x;
            prod[1] *= part[mw + 1] + g0.y;
            prod[2] *= part[mw + 2] + g1.x;
            prod[3] *= part[mw + 3] + g1.y;
        }
        __builtin_nontemporal_store(f32x4{prod[0], prod[1], prod[2], prod[3]},
                                    (f32x4*)(o + r * 32));
    }
}

// ---- fp32 direct fallback (ws too small; not expected in practice) ----
__global__ __launch_bounds__(256) void kp_sample_f32(const float* __restrict__ xs,
                                                     const float* __restrict__ p128,
                                                     const float* __restrict__ p256,
                                                     const float* __restrict__ p512,
                                                     float* __restrict__ out) {
    const int t = blockIdx.x * 256 + (int)threadIdx.x;
    const int n = t >> 5;
    const int c = t & 31;
    const float a = xs[n * 3 + 0], b = xs[n * 3 + 1], d = xs[n * 3 + 2];
    const float gxs[3] = {a, a, b};
    const float gys[3] = {b, d, d};
    const float* planes[3] = {p128, p256, p512};
    const int Rs[3] = {128, 256, 512};
    float* o = out + (size_t)n * 96;
#pragma unroll
    for (int r = 0; r < 3; ++r) {
        const int R = Rs[r];
        const float fr = (float)(R - 1);
        float f = 1.0f;
#pragma unroll
        for (int p = 0; p < 3; ++p) {
            float ix = (gxs[p] + 1.f) * 0.5f * fr;
            float iy = (gys[p] + 1.f) * 0.5f * fr;
            float x0f = fminf(fmaxf(floorf(ix), 0.f), fr);
            float y0f = fminf(fmaxf(floorf(iy), 0.f), fr);
            float wx = ix - x0f, wy = iy - y0f;
            int xi0 = (int)x0f, yi0 = (int)y0f;
            int xi1 = min(xi0 + 1, R - 1), yi1 = min(yi0 + 1, R - 1);
            const float* pc = planes[r] + ((size_t)p * kC + c) * R * R;
            float v00 = pc[yi0 * R + xi0], v01 = pc[yi0 * R + xi1];
            float v10 = pc[yi1 * R + xi0], v11 = pc[yi1 * R + xi1];
            f *= v00 * (1.f - wx) * (1.f - wy) + v01 * wx * (1.f - wy)
               + v10 * (1.f - wx) * wy + v11 * wx * wy;
        }
        __builtin_nontemporal_store(f, o + r * 32 + c);
    }
}

extern "C" void kernel_launch(void* const* d_in, const int* in_sizes, int n_in,
                              void* d_out, int out_size, void* d_ws, size_t ws_size,
                              hipStream_t stream) {
    const float* xs   = (const float*)d_in[0];
    const float* p128 = (const float*)d_in[1];
    const float* p256 = (const float*)d_in[2];
    const float* p512 = (const float*)d_in[3];
    float* out = (float*)d_out;

    const size_t n128 = (size_t)3 * 128 * 128 * kC;
    const size_t n256 = (size_t)3 * 256 * 256 * kC;
    const size_t n512 = (size_t)3 * 512 * 512 * kC;
    const size_t planes_b = (n128 + n256 + n512) * sizeof(__half);
    const size_t sorted_b = (size_t)kN * 16;
    const size_t hist_b   = (size_t)kCells * 4;
    const size_t need = sorted_b + planes_b + 2 * hist_b + 256;

    dim3 tblk(32, 32);
    const int nblk8 = (kN * 8) / 256;   // 32768

    if (ws_size >= need) {
        // ws layout: sorted (16B-aligned) | planes fp16 (contiguous) | hist | cursor
        f32x4* sorted = (f32x4*)d_ws;
        __half* planes = (__half*)((char*)d_ws + sorted_b);
        __half* t128 = planes;
        __half* t256 = t128 + n128;
        __half* t512 = t256 + n256;
        unsigned* hist   = (unsigned*)((char*)d_ws + sorted_b + planes_b);
        unsigned* cursor = hist + kCells;

        kp_transpose_h<<<dim3(128 / 32, 128, 3), tblk, 0, stream>>>(p128, t128, 128);
        kp_transpose_h<<<dim3(256 / 32, 256, 3), tblk, 0, stream>>>(p256, t256, 256);
        kp_transpose_h<<<dim3(512 / 32, 512, 3), tblk, 0, stream>>>(p512, t512, 512);
        kp_zero<<<(kCells + 255) / 256, 256, 0, stream>>>(hist, kCells);
        kp_hist<<<kN / 256, 256, 0, stream>>>(xs, hist);
        kp_scan<<<1, 1024, 0, stream>>>(hist, cursor);
        kp_scatter<<<kN / 256, 256, 0, stream>>>(xs, cursor, sorted);
        kp_sample_dpp<<<nblk8, 256, 0, stream>>>(sorted, planes, out);
    } else {
        kp_sample_f32<<<(kN * 32) / 256, 256, 0, stream>>>(xs, p128, p256, p512, out);
    }
}

// Round 11
// 407.712 us; speedup vs baseline: 1.0868x; 1.0868x over previous
//
#include <hip/hip_runtime.h>
#include <hip/hip_fp16.h>

// K-Planes feature field: N=1M points, C=32 channels, 3 pairs, 3 resolutions.
// out[n, r*32 + c] = prod_p bilinear(plane[r][p][c], coords_p(n))
//
// R10 strategy:
//  - sampler: R3-exact champion (fp16 channel-last planes, Morton sort, fused
//    all-res, 8 lanes/pt, 4ch/lane, XCD swizzle). Frozen: 5 variants all lost.
//  - prep slimmed: half2-store transposes (4B/lane writes, half the blocks),
//    Morton cells 32768 -> 4096 (scan traffic /8, zero /8).

constexpr int kN = 1048576;
constexpr int kC = 32;
constexpr int kCells = 16 * 16 * 16;   // 12-bit Morton key

typedef float f32x4 __attribute__((ext_vector_type(4)));
typedef short s16x4 __attribute__((ext_vector_type(4)));

// ---- transpose+convert (3,C,R,R) fp32 -> (3,R,R,C) fp16, half2 stores ----
// block (16,64): covers a 32c x 64x tile; each thread writes one half2.
__global__ __launch_bounds__(1024) void kp_transpose_h2(const float* __restrict__ in,
                                                        __half2* __restrict__ out, int R) {
    __shared__ float tile[32][65];          // [c][x], padded
    const int tid = threadIdx.y * 16 + threadIdx.x;
    const int rx = tid & 63;                // x 0..63 (coalesced sweep)
    const int rc = tid >> 6;                // c 0..15
    const int x0 = blockIdx.x * 64;
    const int y  = blockIdx.y;
    const int p  = blockIdx.z;
    tile[rc][rx]      = in[(((size_t)p * kC + rc) * R + y) * R + x0 + rx];
    tile[rc + 16][rx] = in[(((size_t)p * kC + rc + 16) * R + y) * R + x0 + rx];
    __syncthreads();
    const int c2 = threadIdx.x;             // 0..15 -> channels 2*c2, 2*c2+1
    const int xl = threadIdx.y;             // 0..63
    out[(((size_t)p * R + y) * R + x0 + xl) * 16 + c2] =
        __floats2half2_rn(tile[2 * c2][xl], tile[2 * c2 + 1][xl]);
}

// ---- Morton cell key (16^3) from coords in [-1,1] ----
__device__ __forceinline__ unsigned cell_key(float x, float y, float z) {
    int cx = min(max((int)((x + 1.f) * 8.f), 0), 15);
    int cy = min(max((int)((y + 1.f) * 8.f), 0), 15);
    int cz = min(max((int)((z + 1.f) * 8.f), 0), 15);
    unsigned m = 0;
#pragma unroll
    for (int b = 0; b < 4; ++b) {
        m |= ((unsigned)((cx >> b) & 1)) << (3 * b);
        m |= ((unsigned)((cy >> b) & 1)) << (3 * b + 1);
        m |= ((unsigned)((cz >> b) & 1)) << (3 * b + 2);
    }
    return m;
}

__global__ __launch_bounds__(256) void kp_zero(unsigned* __restrict__ p, int n) {
    int i = blockIdx.x * 256 + threadIdx.x;
    if (i < n) p[i] = 0u;
}

__global__ __launch_bounds__(256) void kp_hist(const float* __restrict__ xs,
                                               unsigned* __restrict__ hist) {
    int n = blockIdx.x * 256 + threadIdx.x;
    float x = xs[n * 3 + 0], y = xs[n * 3 + 1], z = xs[n * 3 + 2];
    atomicAdd(&hist[cell_key(x, y, z)], 1u);
}

// single-block exclusive scan of kCells entries -> cursor
__global__ __launch_bounds__(1024) void kp_scan(const unsigned* __restrict__ hist,
                                                unsigned* __restrict__ cursor) {
    __shared__ unsigned sums[1024];
    const int t = threadIdx.x;
    const int per = kCells / 1024;          // 4
    unsigned local[per];
    unsigned s = 0;
    const int base = t * per;
#pragma unroll
    for (int i = 0; i < per; ++i) { local[i] = hist[base + i]; s += local[i]; }
    sums[t] = s;
    __syncthreads();
    for (int off = 1; off < 1024; off <<= 1) {
        unsigned v = (t >= off) ? sums[t - off] : 0u;
        __syncthreads();
        sums[t] += v;
        __syncthreads();
    }
    unsigned run = (t == 0) ? 0u : sums[t - 1];   // exclusive prefix
#pragma unroll
    for (int i = 0; i < per; ++i) { cursor[base + i] = run; run += local[i]; }
}

__global__ __launch_bounds__(256) void kp_scatter(const float* __restrict__ xs,
                                                  unsigned* __restrict__ cursor,
                                                  f32x4* __restrict__ sorted) {
    int n = blockIdx.x * 256 + threadIdx.x;
    float x = xs[n * 3 + 0], y = xs[n * 3 + 1], z = xs[n * 3 + 2];
    unsigned pos = atomicAdd(&cursor[cell_key(x, y, z)], 1u);
    f32x4 v = {x, y, z, __uint_as_float((unsigned)n)};
    __builtin_nontemporal_store(v, &sorted[pos]);
}

__device__ __forceinline__ void load4h(const __half* __restrict__ p, float* v) {
    union { s16x4 s; __half2 h[2]; } u;
    u.s = *reinterpret_cast<const s16x4*>(p);   // one 8B load
    float2 f01 = __half22float2(u.h[0]);
    float2 f23 = __half22float2(u.h[1]);
    v[0] = f01.x; v[1] = f01.y; v[2] = f23.x; v[3] = f23.y;
}

template<int R>
__device__ __forceinline__ void sample_res(const __half* __restrict__ planes, int c4,
                                           const float* gx, const float* gy, float* f) {
    const float fr = (float)(R - 1);
    f[0] = f[1] = f[2] = f[3] = 1.f;
#pragma unroll
    for (int p = 0; p < 3; ++p) {
        float ix = (gx[p] + 1.f) * 0.5f * fr;
        float iy = (gy[p] + 1.f) * 0.5f * fr;
        float x0f = fminf(fmaxf(floorf(ix), 0.f), fr);
        float y0f = fminf(fmaxf(floorf(iy), 0.f), fr);
        float wx = ix - x0f, wy = iy - y0f;
        int xi0 = (int)x0f, yi0 = (int)y0f;
        int xi1 = min(xi0 + 1, R - 1), yi1 = min(yi0 + 1, R - 1);
        const __half* pl = planes + (size_t)p * R * R * kC + c4;
        float v00[4], v01[4], v10[4], v11[4];
        load4h(pl + (yi0 * R + xi0) * kC, v00);
        load4h(pl + (yi0 * R + xi1) * kC, v01);
        load4h(pl + (yi1 * R + xi0) * kC, v10);
        load4h(pl + (yi1 * R + xi1) * kC, v11);
        float w00 = (1.f - wx) * (1.f - wy), w01 = wx * (1.f - wy);
        float w10 = (1.f - wx) * wy,         w11 = wx * wy;
#pragma unroll
        for (int j = 0; j < 4; ++j)
            f[j] *= w00 * v00[j] + w01 * v01[j] + w10 * v10[j] + w11 * v11[j];
    }
}

// ---- fused sampler over sorted points: 8 lanes/point, 4 ch/lane (R3 exact) ----
__global__ __launch_bounds__(256) void kp_sample_sorted(const f32x4* __restrict__ pts,
                                                        const __half* __restrict__ t128,
                                                        const __half* __restrict__ t256,
                                                        const __half* __restrict__ t512,
                                                        float* __restrict__ out) {
    const int nwg = (kN * 8) / 256;                 // 32768, %8 == 0
    int bid = blockIdx.x;
    bid = (bid & 7) * (nwg / 8) + (bid >> 3);       // XCD-contiguous chunks
    const int li = threadIdx.x;
    const int n  = bid * 32 + (li >> 3);            // sorted point index
    const int c4 = (li & 7) << 2;
    f32x4 pt = pts[n];
    const float a = pt.x, b = pt.y, d = pt.z;
    const unsigned oi = __float_as_uint(pt.w);
    // PAIRS = (0,1),(0,2),(1,2); coords last dim = (gx, gy)
    const float gx[3] = {a, a, b};
    const float gy[3] = {b, d, d};
    float* o = out + (size_t)oi * 96 + c4;
    float f[4];
    sample_res<128>(t128, c4, gx, gy, f);
    __builtin_nontemporal_store(f32x4{f[0], f[1], f[2], f[3]}, (f32x4*)o);
    sample_res<256>(t256, c4, gx, gy, f);
    __builtin_nontemporal_store(f32x4{f[0], f[1], f[2], f[3]}, (f32x4*)(o + 32));
    sample_res<512>(t512, c4, gx, gy, f);
    __builtin_nontemporal_store(f32x4{f[0], f[1], f[2], f[3]}, (f32x4*)(o + 64));
}

// ---- fp32 direct fallback (ws too small; not expected in practice) ----
__global__ __launch_bounds__(256) void kp_sample_f32(const float* __restrict__ xs,
                                                     const float* __restrict__ p128,
                                                     const float* __restrict__ p256,
                                                     const float* __restrict__ p512,
                                                     float* __restrict__ out) {
    const int t = blockIdx.x * 256 + (int)threadIdx.x;
    const int n = t >> 5;
    const int c = t & 31;
    const float a = xs[n * 3 + 0], b = xs[n * 3 + 1], d = xs[n * 3 + 2];
    const float gxs[3] = {a, a, b};
    const float gys[3] = {b, d, d};
    const float* planes[3] = {p128, p256, p512};
    const int Rs[3] = {128, 256, 512};
    float* o = out + (size_t)n * 96;
#pragma unroll
    for (int r = 0; r < 3; ++r) {
        const int R = Rs[r];
        const float fr = (float)(R - 1);
        float f = 1.0f;
#pragma unroll
        for (int p = 0; p < 3; ++p) {
            float ix = (gxs[p] + 1.f) * 0.5f * fr;
            float iy = (gys[p] + 1.f) * 0.5f * fr;
            float x0f = fminf(fmaxf(floorf(ix), 0.f), fr);
            float y0f = fminf(fmaxf(floorf(iy), 0.f), fr);
            float wx = ix - x0f, wy = iy - y0f;
            int xi0 = (int)x0f, yi0 = (int)y0f;
            int xi1 = min(xi0 + 1, R - 1), yi1 = min(yi0 + 1, R - 1);
            const float* pc = planes[r] + ((size_t)p * kC + c) * R * R;
            float v00 = pc[yi0 * R + xi0], v01 = pc[yi0 * R + xi1];
            float v10 = pc[yi1 * R + xi0], v11 = pc[yi1 * R + xi1];
            f *= v00 * (1.f - wx) * (1.f - wy) + v01 * wx * (1.f - wy)
               + v10 * (1.f - wx) * wy + v11 * wx * wy;
        }
        __builtin_nontemporal_store(f, o + r * 32 + c);
    }
}

extern "C" void kernel_launch(void* const* d_in, const int* in_sizes, int n_in,
                              void* d_out, int out_size, void* d_ws, size_t ws_size,
                              hipStream_t stream) {
    const float* xs   = (const float*)d_in[0];
    const float* p128 = (const float*)d_in[1];
    const float* p256 = (const float*)d_in[2];
    const float* p512 = (const float*)d_in[3];
    float* out = (float*)d_out;

    const size_t n128 = (size_t)3 * 128 * 128 * kC;
    const size_t n256 = (size_t)3 * 256 * 256 * kC;
    const size_t n512 = (size_t)3 * 512 * 512 * kC;
    const size_t planes_b = (n128 + n256 + n512) * sizeof(__half);
    const size_t sorted_b = (size_t)kN * 16;
    const size_t hist_b   = (size_t)kCells * 4;
    const size_t need = sorted_b + planes_b + 2 * hist_b + 256;

    dim3 tblk(16, 64);
    const int nblk8 = (kN * 8) / 256;   // 32768

    if (ws_size >= need) {
        // ws layout: sorted (16B-aligned) | planes fp16 (contiguous) | hist | cursor
        f32x4* sorted = (f32x4*)d_ws;
        __half* planes = (__half*)((char*)d_ws + sorted_b);
        __half* t128 = planes;
        __half* t256 = t128 + n128;
        __half* t512 = t256 + n256;
        unsigned* hist   = (unsigned*)((char*)d_ws + sorted_b + planes_b);
        unsigned* cursor = hist + kCells;

        kp_transpose_h2<<<dim3(128 / 64, 128, 3), tblk, 0, stream>>>(p128, (__half2*)t128, 128);
        kp_transpose_h2<<<dim3(256 / 64, 256, 3), tblk, 0, stream>>>(p256, (__half2*)t256, 256);
        kp_transpose_h2<<<dim3(512 / 64, 512, 3), tblk, 0, stream>>>(p512, (__half2*)t512, 512);
        kp_zero<<<kCells / 256, 256, 0, stream>>>(hist, kCells);
        kp_hist<<<kN / 256, 256, 0, stream>>>(xs, hist);
        kp_scan<<<1, 1024, 0, stream>>>(hist, cursor);
        kp_scatter<<<kN / 256, 256, 0, stream>>>(xs, cursor, sorted);
        kp_sample_sorted<<<nblk8, 256, 0, stream>>>(sorted, t128, t256, t512, out);
    } else {
        kp_sample_f32<<<(kN * 32) / 256, 256, 0, stream>>>(xs, p128, p256, p512, out);
    }
}